// Round 11
// baseline (348.546 us; speedup 1.0000x reference)
//
#include <hip/hip_runtime.h>
#include <cstdint>
#include <cstddef>

typedef __bf16 bf16;
typedef __attribute__((ext_vector_type(8))) __bf16 bf16x8;
typedef __attribute__((ext_vector_type(4))) __bf16 bf16x4;
typedef __attribute__((ext_vector_type(2))) __bf16 bf16x2;
typedef __attribute__((ext_vector_type(4))) float f32x4;

#define MFMA_16x16x32(a, b, c) __builtin_amdgcn_mfma_f32_16x16x32_bf16((a), (b), (c), 0, 0, 0)

__device__ __forceinline__ void gload_lds16(const void* g, void* l) {
  __builtin_amdgcn_global_load_lds((__attribute__((address_space(1))) void*)g,
                                   (__attribute__((address_space(3))) void*)l,
                                   16, 0, 0);
}

// ---------------------------------------------------------------------------
// fp32 -> bf16 convert (grid covers exactly n/4 elements, n = 4096*1024)
// ---------------------------------------------------------------------------
__global__ __launch_bounds__(256) void cvt_x_kernel(const float* __restrict__ in,
                                                    bf16* __restrict__ out) {
  int i = blockIdx.x * 256 + threadIdx.x;
  float4 v = ((const float4*)in)[i];
  bf16x4 o = {(bf16)v.x, (bf16)v.y, (bf16)v.z, (bf16)v.w};
  ((bf16x4*)out)[i] = o;
}

// ---------------------------------------------------------------------------
// transpose + convert: in fp32 [R][C] -> out bf16 [C][R]
// ---------------------------------------------------------------------------
__global__ __launch_bounds__(256) void transpose_cvt_kernel(const float* __restrict__ in,
                                                            bf16* __restrict__ out,
                                                            int R, int C) {
  __shared__ float tile[32][33];
  int tiles_c = C >> 5;
  int br = (int)blockIdx.x / tiles_c, bc = (int)blockIdx.x % tiles_c;
  int r0 = br << 5, c0 = bc << 5;
  int tr = threadIdx.x >> 5, tc = threadIdx.x & 31;
#pragma unroll
  for (int i = 0; i < 4; i++)
    tile[tr + 8 * i][tc] = in[(size_t)(r0 + tr + 8 * i) * C + c0 + tc];
  __syncthreads();
#pragma unroll
  for (int i = 0; i < 4; i++) {
    int oc = tr + 8 * i;
    out[(size_t)(c0 + oc) * R + r0 + tc] = (bf16)tile[tc][oc];
  }
}

// ---------------------------------------------------------------------------
// Fused QKV projection GEMM, 256x192 tile, 8-phase-style schedule (round 9).
// ---------------------------------------------------------------------------
__global__ __launch_bounds__(512, 2) void gemm_fused_qkv(
    const bf16* __restrict__ A, const bf16* __restrict__ Bt,
    const float* __restrict__ q_b, const float* __restrict__ v_b,
    const float* __restrict__ k_b,
    bf16* __restrict__ Qm, bf16* __restrict__ Km, bf16* __restrict__ Vt) {
  constexpr int K = 1024, NT = 16;  // K-tiles of 64
  __shared__ __align__(16) bf16 sA[2][2][256 * 32];  // 64 KB
  __shared__ __align__(16) bf16 sB[2][192 * 64];     // 48 KB

  int bid = blockIdx.x;
  int xcd = bid & 7, j = bid >> 3;
  int bm = xcd * 2 + (j & 1), bn = j >> 1;
  int m0 = bm << 8, n0 = bn * 192;

  int tid = threadIdx.x, lane = tid & 63, w = tid >> 6;
  int wr = w >> 2, wc = w & 3;
  int l15 = lane & 15, lg = lane >> 4;

  int sra = lane >> 2, sca = lane & 3;
  const bf16* gA = A + (size_t)(m0 + w * 32 + sra) * K + ((sca ^ ((sra >> 1) & 3)) * 8);
  int srb = lane >> 3, scb = lane & 7;
  const bf16* gB = Bt + (size_t)(n0 + w * 24 + srb) * K + ((scb ^ srb) * 8);

#define STAGE_A2(BUF, KH, T)                                               \
  {                                                                        \
    _Pragma("unroll") for (int ii = 0; ii < 2; ii++)                       \
        gload_lds16(gA + (size_t)(ii * 16) * K + (T) * 64 + (KH) * 32,     \
                    &sA[BUF][KH][w * 1024 + ii * 512]);                    \
  }
#define STAGE_B3(BUF, T)                                                   \
  {                                                                        \
    _Pragma("unroll") for (int ii = 0; ii < 3; ii++)                       \
        gload_lds16(gB + (size_t)(ii * 8) * K + (T) * 64,                  \
                    &sB[BUF][(w * 3 + ii) * 512]);                         \
  }
#define VMCNT(N) asm volatile("s_waitcnt vmcnt(" #N ")" ::: "memory")
#define LGK0                                           \
  {                                                    \
    asm volatile("s_waitcnt lgkmcnt(0)" ::: "memory"); \
    __builtin_amdgcn_sched_barrier(0);                 \
  }

  int slotA = lg ^ ((l15 >> 1) & 3);
  int aBase = wr * 4096 + l15 * 32 + slotA * 8;
  int bBase = (wc * 48 + l15) * 64;
  int sB0 = (lg ^ (l15 & 7)) * 8;
  int sB1 = ((4 + lg) ^ (l15 & 7)) * 8;

#define RD_A(BUF, KH, MFB)                                                 \
  _Pragma("unroll") for (int mf = 0; mf < 4; mf++)                         \
      a[mf] = *(const bf16x8*)&sA[BUF][KH][aBase + (MFB + mf) * 512];
#define RD_B(BUF, SLOT, BV)                                                \
  _Pragma("unroll") for (int nf = 0; nf < 3; nf++)                         \
      BV[nf] = *(const bf16x8*)&sB[BUF][bBase + nf * 1024 + (SLOT)];
#define MFMA12(MFB, BV)                                                    \
  _Pragma("unroll") for (int mf = 0; mf < 4; mf++)                         \
      _Pragma("unroll") for (int nf = 0; nf < 3; nf++)                     \
          acc[MFB + mf][nf] = MFMA_16x16x32(a[mf], BV[nf], acc[MFB + mf][nf]);

  f32x4 acc[8][3];
#pragma unroll
  for (int mf = 0; mf < 8; mf++)
#pragma unroll
    for (int nf = 0; nf < 3; nf++) acc[mf][nf] = (f32x4){0.f, 0.f, 0.f, 0.f};

  STAGE_B3(0, 0);
  STAGE_A2(0, 0, 0);
  STAGE_A2(0, 1, 0);
  VMCNT(2);
  __builtin_amdgcn_s_barrier();

#pragma unroll 2
  for (int s = 0; s < NT; s++) {
    int buf = s & 1, nbuf = buf ^ 1;
    int nxt = (s + 1) & (NT - 1);
    bf16x8 a[4], b0[3], b1[3];

    // ---- ph1: ks0, mf0-3; stage B(s+1)
    RD_A(buf, 0, 0);
    RD_B(buf, sB0, b0);
    STAGE_B3(nbuf, nxt);
    __builtin_amdgcn_s_barrier();
    LGK0;
    __builtin_amdgcn_s_setprio(1);
    MFMA12(0, b0);
    __builtin_amdgcn_s_setprio(0);
    __builtin_amdgcn_s_barrier();

    // ---- ph2: ks0, mf4-7; stage A0(s+1); vmcnt(5) drains A1(s) for ph3
    RD_A(buf, 0, 4);
    STAGE_A2(nbuf, 0, nxt);
    VMCNT(5);
    __builtin_amdgcn_s_barrier();
    LGK0;
    __builtin_amdgcn_s_setprio(1);
    MFMA12(4, b0);
    __builtin_amdgcn_s_setprio(0);
    __builtin_amdgcn_s_barrier();

    // ---- ph3: ks1, mf0-3; stage A1(s+1)
    RD_A(buf, 1, 0);
    RD_B(buf, sB1, b1);
    STAGE_A2(nbuf, 1, nxt);
    __builtin_amdgcn_s_barrier();
    LGK0;
    __builtin_amdgcn_s_setprio(1);
    MFMA12(0, b1);
    __builtin_amdgcn_s_setprio(0);
    __builtin_amdgcn_s_barrier();

    // ---- ph4: ks1, mf4-7; vmcnt(2) drains B(s+1)+A0(s+1) for next ph1
    RD_A(buf, 1, 4);
    VMCNT(2);
    __builtin_amdgcn_s_barrier();
    LGK0;
    __builtin_amdgcn_s_setprio(1);
    MFMA12(4, b1);
    __builtin_amdgcn_s_setprio(0);
    __builtin_amdgcn_s_barrier();
  }

  // ---- epilogue: route by N-segment (block-uniform; 3072 = 16 tiles x 192)
  int seg = bn >> 4;
  int segbn = bn & 15;
  const float* bias = seg == 0 ? q_b : (seg == 1 ? v_b : k_b);
  bf16* outQK = seg == 0 ? Qm : Km;
#pragma unroll
  for (int mf = 0; mf < 8; mf++) {
#pragma unroll
    for (int nf = 0; nf < 3; nf++) {
      int colL = segbn * 192 + wc * 48 + nf * 16 + l15;
      int row0 = m0 + wr * 128 + mf * 16 + lg * 4;
      float bv = bias[colL];
      if (seg < 2) {
#pragma unroll
        for (int r = 0; r < 4; r++)
          outQK[(size_t)(row0 + r) * 3072 + colL] = (bf16)(acc[mf][nf][r] + bv);
      } else {
        int hh = colL / 192, dd = colL % 192;
        int bi = row0 >> 11, nn = row0 & 2047;
        bf16x4 pk = {(bf16)(acc[mf][nf][0] + bv), (bf16)(acc[mf][nf][1] + bv),
                     (bf16)(acc[mf][nf][2] + bv), (bf16)(acc[mf][nf][3] + bv)};
        *(bf16x4*)(Vt + (((size_t)bi * 16 + hh) * 192 + dd) * 2048 + nn) = pk;
      }
    }
  }
#undef STAGE_A2
#undef STAGE_B3
#undef LGK0
#undef RD_A
#undef RD_B
#undef MFMA12
}

// ---------------------------------------------------------------------------
// bf16 GEMM (m97 structure), used for the final output projection.
// ---------------------------------------------------------------------------
template <int EPI>
__global__ __launch_bounds__(256, 2) void gemm_bf16_kernel(const bf16* __restrict__ A,
                                                           const bf16* __restrict__ Bt,
                                                           const float* __restrict__ bias,
                                                           void* __restrict__ Cout,
                                                           int M, int N, int K) {
  __shared__ __align__(16) bf16 sA[128 * 64];
  __shared__ __align__(16) bf16 sB[128 * 64];
  int tiles_n = N >> 7;
  int bm = (int)blockIdx.x / tiles_n, bn = (int)blockIdx.x % tiles_n;
  int m0 = bm << 7, n0 = bn << 7;
  int tid = threadIdx.x, lane = tid & 63, w = tid >> 6;
  int wr = w >> 1, wc = w & 1;
  int l15 = lane & 15, lg = lane >> 4;
  int sr = lane >> 3, sc = lane & 7;

  f32x4 acc[4][4];
#pragma unroll
  for (int mf = 0; mf < 4; mf++)
#pragma unroll
    for (int nf = 0; nf < 4; nf++) acc[mf][nf] = (f32x4){0.f, 0.f, 0.f, 0.f};

  int nkt = K >> 6;
  for (int kt = 0; kt < nkt; kt++) {
    __syncthreads();
#pragma unroll
    for (int i = 0; i < 4; i++) {
      int iw = w * 4 + i;
      int row = iw * 8 + sr;
      gload_lds16(A + (size_t)(m0 + row) * K + kt * 64 + sc * 8, &sA[iw * 512]);
      gload_lds16(Bt + (size_t)(n0 + row) * K + kt * 64 + sc * 8, &sB[iw * 512]);
    }
    __syncthreads();
#pragma unroll
    for (int ks = 0; ks < 2; ks++) {
      bf16x8 af[4], bfr[4];
#pragma unroll
      for (int mf = 0; mf < 4; mf++)
        af[mf] = *(const bf16x8*)&sA[(wr * 64 + mf * 16 + l15) * 64 + ks * 32 + lg * 8];
#pragma unroll
      for (int nf = 0; nf < 4; nf++)
        bfr[nf] = *(const bf16x8*)&sB[(wc * 64 + nf * 16 + l15) * 64 + ks * 32 + lg * 8];
#pragma unroll
      for (int mf = 0; mf < 4; mf++)
#pragma unroll
        for (int nf = 0; nf < 4; nf++)
          acc[mf][nf] = MFMA_16x16x32(af[mf], bfr[nf], acc[mf][nf]);
    }
  }

#pragma unroll
  for (int mf = 0; mf < 4; mf++) {
#pragma unroll
    for (int nf = 0; nf < 4; nf++) {
      int col = n0 + wc * 64 + nf * 16 + l15;
      int row0 = m0 + wr * 64 + mf * 16 + lg * 4;
      float biasv = bias[col];
      float* out = (float*)Cout;
#pragma unroll
      for (int r = 0; r < 4; r++)
        out[(size_t)(row0 + r) * N + col] = acc[mf][nf][r] + biasv;
    }
  }
}

// ---------------------------------------------------------------------------
// Flash attention v3: r9 geometry (KBLK=64, 8 waves, QBLK=256, grid 256)
// + T15-style intra-wave pipeline: QK^T(t+1) [MFMA] || softmax(t) [VALU]
// are register-independent -> both pipes busy concurrently (m114).
// K double-buffered; V TRIPLE-buffered (stage V(t+2) at iter start is only
// legal because (t+2)%3 != t%3); counted vmcnt(3) each iter drains exactly
// {V(t+1), K(t+2)} one barrier before their reads; never 0 in the loop.
// #pragma unroll 6 folds t&1 / t%3 to constants (no scratch, rule #20).
// ---------------------------------------------------------------------------
__global__ __launch_bounds__(512, 2) void attn_kernel(const bf16* __restrict__ Q,
                                                      const bf16* __restrict__ Km,
                                                      const bf16* __restrict__ Vt,
                                                      bf16* __restrict__ inter) {
  __shared__ __align__(16) bf16 sK[2][64 * 192];      // 48 KB
  __shared__ __align__(16) bf16 sV[3][192 * 64];      // 72 KB
  __shared__ __align__(16) bf16 sPT[8 * 2 * 16 * 72]; // 36 KB

  int i = blockIdx.x;
  int j = i >> 3;
  int bh = (i & 7) * 4 + (j >> 3);
  int qt = j & 7;
  int b = bh >> 4, h = bh & 15;
  int tid = threadIdx.x, lane = tid & 63, w = tid >> 6;
  int l15 = lane & 15, lg = lane >> 4;
  int swz = l15 & 7;

  const bf16* Qh = Q + (size_t)b * 2048 * 3072 + (size_t)h * 192;
  const bf16* Kh = Km + (size_t)b * 2048 * 3072 + (size_t)h * 192;
  const bf16* Vh = Vt + (size_t)bh * 192 * 2048;

  int q0 = qt * 256 + w * 32;

  int kOff[3], vOff[3], ldsOff[3];
#pragma unroll
  for (int ii = 0; ii < 3; ii++) {
    int r = ii * 8 + w;
    int s = r * 64 + lane;
    int krow = s / 24, kc = s % 24;
    int kcs = (kc & 24) | ((kc & 7) ^ (krow & 7));
    kOff[ii] = krow * 3072 + kcs * 8;
    int vrow = s >> 3, vc = s & 7;
    int vcs = vc ^ (vrow & 7);
    vOff[ii] = vrow * 2048 + vcs * 8;
    ldsOff[ii] = r * 512;
  }

#define STAGE_K(BUF, KT)                                                     \
  {                                                                          \
    int kb = (KT) * 64;                                                      \
    _Pragma("unroll") for (int ii = 0; ii < 3; ii++)                         \
        gload_lds16(Kh + (size_t)kb * 3072 + kOff[ii], &sK[BUF][ldsOff[ii]]); \
  }
#define STAGE_V(BUF, KT)                                                     \
  {                                                                          \
    int kb = (KT) * 64;                                                      \
    _Pragma("unroll") for (int ii = 0; ii < 3; ii++)                         \
        gload_lds16(Vh + kb + vOff[ii], &sV[BUF][ldsOff[ii]]);               \
  }

  // prologue stage: K(0),V(0),K(1),V(1)  (12 loads/wave)
  STAGE_K(0, 0);
  STAGE_V(0, 0);
  STAGE_K(1, 1);
  STAGE_V(1, 1);

  bf16x8 aq[2][6];
#pragma unroll
  for (int rf = 0; rf < 2; rf++)
#pragma unroll
    for (int kc = 0; kc < 6; kc++)
      aq[rf][kc] = *(const bf16x8*)(Qh + (size_t)(q0 + rf * 16 + l15) * 3072 + kc * 32 + lg * 8);

  f32x4 o[2][12];
#pragma unroll
  for (int rf = 0; rf < 2; rf++)
#pragma unroll
    for (int df = 0; df < 12; df++) o[rf][df] = (f32x4){0.f, 0.f, 0.f, 0.f};
  float mrow[2] = {-1e30f, -1e30f};
  float lrow[2] = {0.f, 0.f};
  const float scl2 = 0.03125f * 1.44269504f;

  bf16* myPT0 = &sPT[((w * 2 + 0) * 16 + l15) * 72];
  bf16* myPT1 = &sPT[((w * 2 + 1) * 16 + l15) * 72];

  f32x4 st[2][4][2];

  // QK^T into ST from KBUF (no setprio: let scheduler interleave with softmax)
#define QKT(ST, KBUF)                                                        \
  {                                                                          \
    _Pragma("unroll") for (int kf = 0; kf < 4; kf++)                         \
        _Pragma("unroll") for (int rf = 0; rf < 2; rf++)                     \
            ST[kf][rf] = (f32x4){0.f, 0.f, 0.f, 0.f};                        \
    _Pragma("unroll") for (int kc = 0; kc < 6; kc++) {                       \
      int g = kc * 4 + lg;                                                   \
      int cc = (g & 24) | ((g & 7) ^ swz);                                   \
      _Pragma("unroll") for (int kf = 0; kf < 4; kf++) {                     \
        bf16x8 bk = *(const bf16x8*)&(KBUF)[(kf * 16 + l15) * 192 + cc * 8]; \
        ST[kf][0] = MFMA_16x16x32(bk, aq[0][kc], ST[kf][0]);                 \
        ST[kf][1] = MFMA_16x16x32(bk, aq[1][kc], ST[kf][1]);                 \
      }                                                                      \
    }                                                                        \
  }

  // softmax(ST) -> sPT -> P-frags -> PV from VBUF
#define SM_PV(ST, VBUF)                                                      \
  {                                                                          \
    _Pragma("unroll") for (int rf = 0; rf < 2; rf++) {                       \
      bf16* myPT = rf ? myPT1 : myPT0;                                       \
      float mk[4];                                                           \
      _Pragma("unroll") for (int kf = 0; kf < 4; kf++)                       \
          mk[kf] = fmaxf(fmaxf(ST[kf][rf][0], ST[kf][rf][1]),                \
                         fmaxf(ST[kf][rf][2], ST[kf][rf][3]));               \
      float pmx = fmaxf(fmaxf(mk[0], mk[1]), fmaxf(mk[2], mk[3]));           \
      pmx = fmaxf(pmx, __shfl_xor(pmx, 16));                                 \
      pmx = fmaxf(pmx, __shfl_xor(pmx, 32));                                 \
      float pms = pmx * scl2;                                                \
      float mn = mrow[rf];                                                   \
      if (!__all(pms - mn <= 11.0f)) {                                       \
        mn = fmaxf(mn, pms);                                                 \
        float corr = exp2f(mrow[rf] - mn);                                   \
        mrow[rf] = mn;                                                       \
        lrow[rf] *= corr;                                                    \
        _Pragma("unroll") for (int df = 0; df < 12; df++) o[rf][df] *= corr; \
      }                                                                      \
      float skf[4];                                                          \
      _Pragma("unroll") for (int kf = 0; kf < 4; kf++) {                     \
        float e0 = exp2f(fmaf(ST[kf][rf][0], scl2, -mn));                    \
        float e1 = exp2f(fmaf(ST[kf][rf][1], scl2, -mn));                    \
        float e2 = exp2f(fmaf(ST[kf][rf][2], scl2, -mn));                    \
        float e3 = exp2f(fmaf(ST[kf][rf][3], scl2, -mn));                    \
        skf[kf] = (e0 + e1) + (e2 + e3);                                     \
        bf16x4 pk4 = {(bf16)e0, (bf16)e1, (bf16)e2, (bf16)e3};               \
        *(bf16x4*)&myPT[kf * 16 + 4 * lg] = pk4;                             \
      }                                                                      \
      float rs = (skf[0] + skf[1]) + (skf[2] + skf[3]);                      \
      rs += __shfl_xor(rs, 16);                                              \
      rs += __shfl_xor(rs, 32);                                              \
      lrow[rf] += rs;                                                        \
    }                                                                        \
    bf16x8 pf[2][2];                                                         \
    _Pragma("unroll") for (int rf = 0; rf < 2; rf++) {                       \
      bf16* myPT = rf ? myPT1 : myPT0;                                       \
      _Pragma("unroll") for (int ks = 0; ks < 2; ks++)                       \
          pf[rf][ks] = *(const bf16x8*)&myPT[ks * 32 + lg * 8];              \
    }                                                                        \
    __builtin_amdgcn_s_setprio(1);                                           \
    _Pragma("unroll") for (int ks = 0; ks < 2; ks++) {                       \
      int cv = (ks * 4 + lg) ^ swz;                                          \
      _Pragma("unroll") for (int df = 0; df < 12; df++) {                    \
        bf16x8 av = *(const bf16x8*)&(VBUF)[(df * 16 + l15) * 64 + cv * 8];  \
        o[0][df] = MFMA_16x16x32(av, pf[0][ks], o[0][df]);                   \
        o[1][df] = MFMA_16x16x32(av, pf[1][ks], o[1][df]);                   \
      }                                                                      \
    }                                                                        \
    __builtin_amdgcn_s_setprio(0);                                           \
  }

  // prologue: drain K(0) (9 newer may fly); QK^T(0); drain V(0)+K(1)
  VMCNT(9);
  __builtin_amdgcn_s_barrier();
  QKT(st[0], sK[0]);
  VMCNT(3);
  __builtin_amdgcn_s_barrier();

#pragma unroll 6
  for (int t = 0; t < 30; t++) {
    // step0: stage K(t+2) -> sK[t&1] (free: last read was QK^T(t) in iter t-1)
    //        stage V(t+2) -> sV[(t+2)%3] (free: last read was PV(t-1))
    STAGE_K(t & 1, t + 2);
    STAGE_V((t + 2) % 3, t + 2);
    // step1: QK^T(t+1) [MFMA] || softmax(t)+PV(t) [VALU+MFMA] - independent
    QKT(st[(t + 1) & 1], sK[(t + 1) & 1]);
    SM_PV(st[t & 1], sV[t % 3]);
    // step2: drain {V(t+1), K(t+2)}; V(t+2) stays in flight
    VMCNT(3);
    __builtin_amdgcn_s_barrier();
  }

  // peeled t=30: no staging; drain V(31) fully
  QKT(st[1], sK[1]);       // QK^T(31)
  SM_PV(st[0], sV[0]);     // softmax(30)+PV(30)  (30%3==0)
  VMCNT(0);
  __builtin_amdgcn_s_barrier();
  // tile 31
  SM_PV(st[1], sV[1]);     // 31%3==1

  // epilogue: normalize, vectorized bf16x4 stores
#pragma unroll
  for (int rf = 0; rf < 2; rf++) {
    float inv = 1.0f / lrow[rf];
    size_t token = (size_t)b * 2048 + q0 + rf * 16 + l15;
    bf16* outp = inter + token * 3072 + h * 192 + lg * 4;
#pragma unroll
    for (int df = 0; df < 12; df++) {
      bf16x4 pk = {(bf16)(o[rf][df][0] * inv), (bf16)(o[rf][df][1] * inv),
                   (bf16)(o[rf][df][2] * inv), (bf16)(o[rf][df][3] * inv)};
      *(bf16x4*)(outp + df * 16) = pk;
    }
  }
#undef STAGE_K
#undef STAGE_V
#undef QKT
#undef SM_PV
#undef VMCNT
}

// ---------------------------------------------------------------------------
extern "C" void kernel_launch(void* const* d_in, const int* in_sizes, int n_in,
                              void* d_out, int out_size, void* d_ws, size_t ws_size,
                              hipStream_t stream) {
  const float* X = (const float*)d_in[0];
  const float* q_w = (const float*)d_in[1];
  const float* q_b = (const float*)d_in[2];
  const float* k_w = (const float*)d_in[3];
  const float* k_b = (const float*)d_in[4];
  const float* v_w = (const float*)d_in[5];
  const float* v_b = (const float*)d_in[6];
  const float* o_w = (const float*)d_in[7];
  const float* o_b = (const float*)d_in[8];

  char* ws = (char*)d_ws;
  // Wqt/Wvt/Wkt are contiguous: together one [9216][1024] bf16 matrix.
  bf16* Xb  = (bf16*)(ws);                    //  8 MiB: X bf16 [4096][1024]
  bf16* Wqt = (bf16*)(ws + 8388608);          //  6 MiB: q_w^T [3072][1024]
  bf16* Wvt = (bf16*)(ws + 14680064);         //  6 MiB: v_w^T (-> k_mat)
  bf16* Wkt = (bf16*)(ws + 20971520);         //  6 MiB: k_w^T (-> v_mat)
  bf16* Wot = (bf16*)(ws + 27262976);         //  6 MiB: o_w^T [1024][3072]
  bf16* Qm  = (bf16*)(ws + 33554432);         // 24 MiB: Q [4096][3072]
  bf16* Km  = (bf16*)(ws + 58720256);         // 24 MiB: K-attn [4096][3072]
  bf16* Vtw = (bf16*)(ws + 83886080);         // 24 MiB: V-attn^T [32][192][2048]
  bf16* Im  = (bf16*)(ws + 109051904);        // 24 MiB: inter [4096][3072]

  cvt_x_kernel<<<4096, 256, 0, stream>>>(X, Xb);
  transpose_cvt_kernel<<<3072, 256, 0, stream>>>(q_w, Wqt, 1024, 3072);
  transpose_cvt_kernel<<<3072, 256, 0, stream>>>(v_w, Wvt, 1024, 3072);
  transpose_cvt_kernel<<<3072, 256, 0, stream>>>(k_w, Wkt, 1024, 3072);
  transpose_cvt_kernel<<<3072, 256, 0, stream>>>(o_w, Wot, 3072, 1024);

  // fused Q/K/V projection (quirk: seg1 = X@v_w+v_b -> Km, seg2 = X@k_w+k_b -> V)
  gemm_fused_qkv<<<768, 512, 0, stream>>>(Xb, Wqt, q_b, v_b, k_b, Qm, Km, Vtw);

  attn_kernel<<<256, 512, 0, stream>>>(Qm, Km, Vtw, Im);

  gemm_bf16_kernel<2><<<256, 256, 0, stream>>>(Im, Wot, o_b, d_out, 4096, 1024, 3072);
}

// Round 12
// 304.797 us; speedup vs baseline: 1.1435x; 1.1435x over previous
//
#include <hip/hip_runtime.h>
#include <cstdint>
#include <cstddef>

typedef __bf16 bf16;
typedef __attribute__((ext_vector_type(8))) __bf16 bf16x8;
typedef __attribute__((ext_vector_type(4))) __bf16 bf16x4;
typedef __attribute__((ext_vector_type(2))) __bf16 bf16x2;
typedef __attribute__((ext_vector_type(4))) float f32x4;

#define MFMA_16x16x32(a, b, c) __builtin_amdgcn_mfma_f32_16x16x32_bf16((a), (b), (c), 0, 0, 0)

__device__ __forceinline__ void gload_lds16(const void* g, void* l) {
  __builtin_amdgcn_global_load_lds((__attribute__((address_space(1))) void*)g,
                                   (__attribute__((address_space(3))) void*)l,
                                   16, 0, 0);
}

// ---------------------------------------------------------------------------
// fp32 -> bf16 convert (grid covers exactly n/4 elements, n = 4096*1024)
// ---------------------------------------------------------------------------
__global__ __launch_bounds__(256) void cvt_x_kernel(const float* __restrict__ in,
                                                    bf16* __restrict__ out) {
  int i = blockIdx.x * 256 + threadIdx.x;
  float4 v = ((const float4*)in)[i];
  bf16x4 o = {(bf16)v.x, (bf16)v.y, (bf16)v.z, (bf16)v.w};
  ((bf16x4*)out)[i] = o;
}

// ---------------------------------------------------------------------------
// transpose + convert: in fp32 [R][C] -> out bf16 [C][R]
// ---------------------------------------------------------------------------
__global__ __launch_bounds__(256) void transpose_cvt_kernel(const float* __restrict__ in,
                                                            bf16* __restrict__ out,
                                                            int R, int C) {
  __shared__ float tile[32][33];
  int tiles_c = C >> 5;
  int br = (int)blockIdx.x / tiles_c, bc = (int)blockIdx.x % tiles_c;
  int r0 = br << 5, c0 = bc << 5;
  int tr = threadIdx.x >> 5, tc = threadIdx.x & 31;
#pragma unroll
  for (int i = 0; i < 4; i++)
    tile[tr + 8 * i][tc] = in[(size_t)(r0 + tr + 8 * i) * C + c0 + tc];
  __syncthreads();
#pragma unroll
  for (int i = 0; i < 4; i++) {
    int oc = tr + 8 * i;
    out[(size_t)(c0 + oc) * R + r0 + tc] = (bf16)tile[tc][oc];
  }
}

// ---------------------------------------------------------------------------
// Fused QKV projection GEMM v3: 128x192 tile, 2 blocks/CU (TLP covers
// latency), 2-phase / 2-barrier / counted-vmcnt(5) per K-tile.
// A [4096][1024] bf16; Bt [9216][1024] bf16 = Wq^T | Wv^T | Wk^T contiguous.
// Out: seg0 -> Qm (+q_b), seg1 -> Km (+v_b), seg2 -> Vt transposed (+k_b).
// 512 thr = 8 waves (2M x 4N); per-wave out 64x48 (acc[4][3] f32x4).
// Grid 1536 (32 bm x 48 bn) = 6.0 full rounds at 2 blocks/CU (LDS 80 KB).
// LDS: A [dbuf][kh][128x32] chunk-swizzled (slot = lg ^ ((row>>1)&3)),
//      B [dbuf][192x64] row-swizzled (slot ^ row&7); inverse swizzle on
//      per-lane global source, forward on ds_read (G21 both-sides).
// Ledger: stage all 5 loads of (s+1) at iter top; vmcnt(5) drains exactly
// tile s (issued one full iter earlier); ph2 ends lgkmcnt(0)+barrier so the
// next iter's STAGE never overwrites LDS still being read.  Residual vmcnt
// stall is covered by the co-resident second block (16 waves/CU).
// ---------------------------------------------------------------------------
__global__ __launch_bounds__(512, 2) void gemm_fused_qkv(
    const bf16* __restrict__ A, const bf16* __restrict__ Bt,
    const float* __restrict__ q_b, const float* __restrict__ v_b,
    const float* __restrict__ k_b,
    bf16* __restrict__ Qm, bf16* __restrict__ Km, bf16* __restrict__ Vt) {
  constexpr int K = 1024, NT = 16;  // K-tiles of 64
  __shared__ __align__(16) bf16 sA[2][2][128 * 32];  // 32 KB
  __shared__ __align__(16) bf16 sB[2][192 * 64];     // 48 KB

  // XCD swizzle: 1536 = 8 XCDs x 192; per XCD 4 bm x 48 bn.
  int bid = blockIdx.x;
  int xcd = bid & 7, j = bid >> 3;           // j 0..191
  int bm = xcd * 4 + (j & 3), bn = j >> 2;   // bm 0..31, bn 0..47
  int m0 = bm << 7, n0 = bn * 192;

  int tid = threadIdx.x, lane = tid & 63, w = tid >> 6;
  int wr = w >> 2, wc = w & 3;
  int l15 = lane & 15, lg = lane >> 4;

  // A staging: per kh, one 16-row x 4-chunk region per wave (inverse swizzle)
  int sra = lane >> 2, sca = lane & 3;
  const bf16* gA = A + (size_t)(m0 + w * 16 + sra) * K + ((sca ^ ((sra >> 1) & 3)) * 8);
  // B staging: 3 regions per wave (8 rows x 8 chunks each)
  int srb = lane >> 3, scb = lane & 7;
  const bf16* gB = Bt + (size_t)(n0 + w * 24 + srb) * K + ((scb ^ srb) * 8);

#define STAGE_AB(BUF, T)                                                   \
  {                                                                        \
    _Pragma("unroll") for (int kh = 0; kh < 2; kh++)                       \
        gload_lds16(gA + (size_t)(T) * 64 + kh * 32, &sA[BUF][kh][w * 512]); \
    _Pragma("unroll") for (int ii = 0; ii < 3; ii++)                       \
        gload_lds16(gB + (size_t)(ii * 8) * K + (T) * 64,                  \
                    &sB[BUF][(w * 3 + ii) * 512]);                         \
  }
#define VMCNT(N) asm volatile("s_waitcnt vmcnt(" #N ")" ::: "memory")
#define LGK0                                           \
  {                                                    \
    asm volatile("s_waitcnt lgkmcnt(0)" ::: "memory"); \
    __builtin_amdgcn_sched_barrier(0);                 \
  }

  // read offsets (forward swizzle)
  int slotA = lg ^ ((l15 >> 1) & 3);
  int aBase = wr * 2048 + l15 * 32 + slotA * 8;  // + mf*512 within sA[buf][kh]
  int bBase = (wc * 48 + l15) * 64;              // + nf*1024
  int sB0 = (lg ^ (l15 & 7)) * 8;                // ks0 slot
  int sB1 = ((4 + lg) ^ (l15 & 7)) * 8;          // ks1 slot

#define RD_A(BUF, KH)                                                      \
  _Pragma("unroll") for (int mf = 0; mf < 4; mf++)                         \
      a[mf] = *(const bf16x8*)&sA[BUF][KH][aBase + mf * 512];
#define RD_B(BUF, SLOT)                                                    \
  _Pragma("unroll") for (int nf = 0; nf < 3; nf++)                         \
      b[nf] = *(const bf16x8*)&sB[BUF][bBase + nf * 1024 + (SLOT)];
#define MFMA12                                                             \
  _Pragma("unroll") for (int mf = 0; mf < 4; mf++)                         \
      _Pragma("unroll") for (int nf = 0; nf < 3; nf++)                     \
          acc[mf][nf] = MFMA_16x16x32(a[mf], b[nf], acc[mf][nf]);

  f32x4 acc[4][3];
#pragma unroll
  for (int mf = 0; mf < 4; mf++)
#pragma unroll
    for (int nf = 0; nf < 3; nf++) acc[mf][nf] = (f32x4){0.f, 0.f, 0.f, 0.f};

  STAGE_AB(0, 0);  // prologue: tile 0 (5 loads/wave)

#pragma unroll 2
  for (int s = 0; s < NT; s++) {
    int buf = s & 1, nbuf = buf ^ 1;
    int nxt = (s + 1) & (NT - 1);
    bf16x8 a[4], b[3];

    STAGE_AB(nbuf, nxt);  // 5 loads for tile s+1 (wraps harmlessly at s=15)
    VMCNT(5);             // drain exactly tile s (issued one full iter ago)
    __builtin_amdgcn_s_barrier();

    // ---- ph1: ks0
    RD_A(buf, 0);
    RD_B(buf, sB0);
    LGK0;
    __builtin_amdgcn_s_setprio(1);
    MFMA12;
    __builtin_amdgcn_s_setprio(0);

    // ---- ph2: ks1 (reads complete before release barrier)
    RD_A(buf, 1);
    RD_B(buf, sB1);
    LGK0;
    __builtin_amdgcn_s_barrier();  // release buf for next iter's STAGE
    __builtin_amdgcn_s_setprio(1);
    MFMA12;
    __builtin_amdgcn_s_setprio(0);
  }

  // ---- epilogue: route by N-segment (block-uniform; seg = bn/16)
  int seg = bn >> 4;
  int segbn = bn & 15;
  const float* bias = seg == 0 ? q_b : (seg == 1 ? v_b : k_b);
  bf16* outQK = seg == 0 ? Qm : Km;
#pragma unroll
  for (int mf = 0; mf < 4; mf++) {
#pragma unroll
    for (int nf = 0; nf < 3; nf++) {
      int colL = segbn * 192 + wc * 48 + nf * 16 + l15;
      int row0 = m0 + wr * 64 + mf * 16 + lg * 4;
      float bv = bias[colL];
      if (seg < 2) {
#pragma unroll
        for (int r = 0; r < 4; r++)
          outQK[(size_t)(row0 + r) * 3072 + colL] = (bf16)(acc[mf][nf][r] + bv);
      } else {
        int hh = colL / 192, dd = colL % 192;
        int bi = row0 >> 11, nn = row0 & 2047;
        bf16x4 pk = {(bf16)(acc[mf][nf][0] + bv), (bf16)(acc[mf][nf][1] + bv),
                     (bf16)(acc[mf][nf][2] + bv), (bf16)(acc[mf][nf][3] + bv)};
        *(bf16x4*)(Vt + (((size_t)bi * 16 + hh) * 192 + dd) * 2048 + nn) = pk;
      }
    }
  }
#undef STAGE_AB
#undef VMCNT
#undef LGK0
#undef RD_A
#undef RD_B
#undef MFMA12
}

// ---------------------------------------------------------------------------
// bf16 GEMM (m97 structure), used for the final output projection.
// C[m][n] = sum_k A[m][k] * Bt[n][k] + bias[n]; fp32 out [M][N].
// ---------------------------------------------------------------------------
template <int EPI>
__global__ __launch_bounds__(256, 2) void gemm_bf16_kernel(const bf16* __restrict__ A,
                                                           const bf16* __restrict__ Bt,
                                                           const float* __restrict__ bias,
                                                           void* __restrict__ Cout,
                                                           int M, int N, int K) {
  __shared__ __align__(16) bf16 sA[128 * 64];
  __shared__ __align__(16) bf16 sB[128 * 64];
  int tiles_n = N >> 7;
  int bm = (int)blockIdx.x / tiles_n, bn = (int)blockIdx.x % tiles_n;
  int m0 = bm << 7, n0 = bn << 7;
  int tid = threadIdx.x, lane = tid & 63, w = tid >> 6;
  int wr = w >> 1, wc = w & 1;
  int l15 = lane & 15, lg = lane >> 4;
  int sr = lane >> 3, sc = lane & 7;

  f32x4 acc[4][4];
#pragma unroll
  for (int mf = 0; mf < 4; mf++)
#pragma unroll
    for (int nf = 0; nf < 4; nf++) acc[mf][nf] = (f32x4){0.f, 0.f, 0.f, 0.f};

  int nkt = K >> 6;
  for (int kt = 0; kt < nkt; kt++) {
    __syncthreads();
#pragma unroll
    for (int i = 0; i < 4; i++) {
      int iw = w * 4 + i;
      int row = iw * 8 + sr;
      gload_lds16(A + (size_t)(m0 + row) * K + kt * 64 + sc * 8, &sA[iw * 512]);
      gload_lds16(Bt + (size_t)(n0 + row) * K + kt * 64 + sc * 8, &sB[iw * 512]);
    }
    __syncthreads();
#pragma unroll
    for (int ks = 0; ks < 2; ks++) {
      bf16x8 af[4], bfr[4];
#pragma unroll
      for (int mf = 0; mf < 4; mf++)
        af[mf] = *(const bf16x8*)&sA[(wr * 64 + mf * 16 + l15) * 64 + ks * 32 + lg * 8];
#pragma unroll
      for (int nf = 0; nf < 4; nf++)
        bfr[nf] = *(const bf16x8*)&sB[(wc * 64 + nf * 16 + l15) * 64 + ks * 32 + lg * 8];
#pragma unroll
      for (int mf = 0; mf < 4; mf++)
#pragma unroll
        for (int nf = 0; nf < 4; nf++)
          acc[mf][nf] = MFMA_16x16x32(af[mf], bfr[nf], acc[mf][nf]);
    }
  }

#pragma unroll
  for (int mf = 0; mf < 4; mf++) {
#pragma unroll
    for (int nf = 0; nf < 4; nf++) {
      int col = n0 + wc * 64 + nf * 16 + l15;
      int row0 = m0 + wr * 64 + mf * 16 + lg * 4;
      float biasv = bias[col];
      float* out = (float*)Cout;
#pragma unroll
      for (int r = 0; r < 4; r++)
        out[(size_t)(row0 + r) * N + col] = acc[mf][nf][r] + biasv;
    }
  }
}

// ---------------------------------------------------------------------------
// Flash attention (r5/r9 known-good version): swapped-S^T, global_load_lds
// double-buffered K/V, 8 waves x 32 q-rows, XOR-swizzled both-sides staging.
// ---------------------------------------------------------------------------
__global__ __launch_bounds__(512, 2) void attn_kernel(const bf16* __restrict__ Q,
                                                      const bf16* __restrict__ Km,
                                                      const bf16* __restrict__ Vt,
                                                      bf16* __restrict__ inter) {
  __shared__ __align__(16) bf16 sK[2][64 * 192];
  __shared__ __align__(16) bf16 sV[2][192 * 64];
  __shared__ __align__(16) bf16 sPT[8 * 2 * 16 * 72];

  int i = blockIdx.x;
  int j = i >> 3;
  int bh = (i & 7) * 4 + (j >> 3);
  int qt = j & 7;
  int b = bh >> 4, h = bh & 15;
  int tid = threadIdx.x, lane = tid & 63, w = tid >> 6;
  int l15 = lane & 15, lg = lane >> 4;
  int swz = l15 & 7;

  const bf16* Qh = Q + (size_t)b * 2048 * 3072 + (size_t)h * 192;
  const bf16* Kh = Km + (size_t)b * 2048 * 3072 + (size_t)h * 192;
  const bf16* Vh = Vt + (size_t)bh * 192 * 2048;

  int q0 = qt * 256 + w * 32;

  int kOff[3], vOff[3], ldsOff[3];
#pragma unroll
  for (int ii = 0; ii < 3; ii++) {
    int r = ii * 8 + w;
    int s = r * 64 + lane;
    int krow = s / 24, kc = s % 24;
    int kcs = (kc & 24) | ((kc & 7) ^ (krow & 7));
    kOff[ii] = krow * 3072 + kcs * 8;
    int vrow = s >> 3, vc = s & 7;
    int vcs = vc ^ (vrow & 7);
    vOff[ii] = vrow * 2048 + vcs * 8;
    ldsOff[ii] = r * 512;
  }

#define STAGE(BUF, KT)                                                      \
  {                                                                         \
    int kb = (KT) * 64;                                                     \
    _Pragma("unroll") for (int ii = 0; ii < 3; ii++) {                      \
      gload_lds16(Kh + (size_t)kb * 3072 + kOff[ii], &sK[BUF][ldsOff[ii]]); \
      gload_lds16(Vh + kb + vOff[ii], &sV[BUF][ldsOff[ii]]);                \
    }                                                                       \
  }

  STAGE(0, 0);

  bf16x8 aq[2][6];
#pragma unroll
  for (int rf = 0; rf < 2; rf++)
#pragma unroll
    for (int kc = 0; kc < 6; kc++)
      aq[rf][kc] = *(const bf16x8*)(Qh + (size_t)(q0 + rf * 16 + l15) * 3072 + kc * 32 + lg * 8);

  f32x4 o[2][12];
#pragma unroll
  for (int rf = 0; rf < 2; rf++)
#pragma unroll
    for (int df = 0; df < 12; df++) o[rf][df] = (f32x4){0.f, 0.f, 0.f, 0.f};
  float mrow[2] = {-1e30f, -1e30f};
  float lrow[2] = {0.f, 0.f};

  const float scl2 = 0.03125f * 1.44269504f;

  bf16* myPT0 = &sPT[((w * 2 + 0) * 16 + l15) * 72];
  bf16* myPT1 = &sPT[((w * 2 + 1) * 16 + l15) * 72];

  __syncthreads();

  for (int kt = 0; kt < 32; kt++) {
    const bf16* kbuf = sK[kt & 1];
    const bf16* vbuf = sV[kt & 1];
    if (kt < 31) STAGE((kt & 1) ^ 1, kt + 1);

    f32x4 st[4][2];
#pragma unroll
    for (int kf = 0; kf < 4; kf++)
#pragma unroll
      for (int rf = 0; rf < 2; rf++) st[kf][rf] = (f32x4){0.f, 0.f, 0.f, 0.f};
    __builtin_amdgcn_s_setprio(1);
#pragma unroll
    for (int kc = 0; kc < 6; kc++) {
      int g = kc * 4 + lg;
      int cc = (g & 24) | ((g & 7) ^ swz);
#pragma unroll
      for (int kf = 0; kf < 4; kf++) {
        bf16x8 bk = *(const bf16x8*)&kbuf[(kf * 16 + l15) * 192 + cc * 8];
        st[kf][0] = MFMA_16x16x32(bk, aq[0][kc], st[kf][0]);
        st[kf][1] = MFMA_16x16x32(bk, aq[1][kc], st[kf][1]);
      }
    }
    __builtin_amdgcn_s_setprio(0);

#pragma unroll
    for (int rf = 0; rf < 2; rf++) {
      bf16* myPT = rf ? myPT1 : myPT0;
      float mk[4];
#pragma unroll
      for (int kf = 0; kf < 4; kf++)
        mk[kf] = fmaxf(fmaxf(st[kf][rf][0], st[kf][rf][1]),
                       fmaxf(st[kf][rf][2], st[kf][rf][3]));
      float pmx = fmaxf(fmaxf(mk[0], mk[1]), fmaxf(mk[2], mk[3]));
      pmx = fmaxf(pmx, __shfl_xor(pmx, 16));
      pmx = fmaxf(pmx, __shfl_xor(pmx, 32));
      float pms = pmx * scl2;

      float mn = mrow[rf];
      if (!__all(pms - mn <= 11.0f)) {
        mn = fmaxf(mn, pms);
        float corr = exp2f(mrow[rf] - mn);
        mrow[rf] = mn;
        lrow[rf] *= corr;
#pragma unroll
        for (int df = 0; df < 12; df++) o[rf][df] *= corr;
      }

      float skf[4];
#pragma unroll
      for (int kf = 0; kf < 4; kf++) {
        float e0 = exp2f(fmaf(st[kf][rf][0], scl2, -mn));
        float e1 = exp2f(fmaf(st[kf][rf][1], scl2, -mn));
        float e2 = exp2f(fmaf(st[kf][rf][2], scl2, -mn));
        float e3 = exp2f(fmaf(st[kf][rf][3], scl2, -mn));
        skf[kf] = (e0 + e1) + (e2 + e3);
        bf16x4 pk4 = {(bf16)e0, (bf16)e1, (bf16)e2, (bf16)e3};
        *(bf16x4*)&myPT[kf * 16 + 4 * lg] = pk4;
      }
      float rs = (skf[0] + skf[1]) + (skf[2] + skf[3]);
      rs += __shfl_xor(rs, 16);
      rs += __shfl_xor(rs, 32);
      lrow[rf] += rs;
    }

    bf16x8 pf[2][2];
#pragma unroll
    for (int rf = 0; rf < 2; rf++) {
      bf16* myPT = rf ? myPT1 : myPT0;
#pragma unroll
      for (int ks = 0; ks < 2; ks++)
        pf[rf][ks] = *(const bf16x8*)&myPT[ks * 32 + lg * 8];
    }

    __builtin_amdgcn_s_setprio(1);
#pragma unroll
    for (int ks = 0; ks < 2; ks++) {
      int cv = (ks * 4 + lg) ^ swz;
#pragma unroll
      for (int df = 0; df < 12; df++) {
        bf16x8 av = *(const bf16x8*)&vbuf[(df * 16 + l15) * 64 + cv * 8];
        o[0][df] = MFMA_16x16x32(av, pf[0][ks], o[0][df]);
        o[1][df] = MFMA_16x16x32(av, pf[1][ks], o[1][df]);
      }
    }
    __builtin_amdgcn_s_setprio(0);

    __syncthreads();
  }

#pragma unroll
  for (int rf = 0; rf < 2; rf++) {
    float inv = 1.0f / lrow[rf];
    size_t token = (size_t)b * 2048 + q0 + rf * 16 + l15;
    bf16* outp = inter + token * 3072 + h * 192 + lg * 4;
#pragma unroll
    for (int df = 0; df < 12; df++) {
      bf16x4 pk = {(bf16)(o[rf][df][0] * inv), (bf16)(o[rf][df][1] * inv),
                   (bf16)(o[rf][df][2] * inv), (bf16)(o[rf][df][3] * inv)};
      *(bf16x4*)(outp + df * 16) = pk;
    }
  }
#undef STAGE
}

// ---------------------------------------------------------------------------
extern "C" void kernel_launch(void* const* d_in, const int* in_sizes, int n_in,
                              void* d_out, int out_size, void* d_ws, size_t ws_size,
                              hipStream_t stream) {
  const float* X = (const float*)d_in[0];
  const float* q_w = (const float*)d_in[1];
  const float* q_b = (const float*)d_in[2];
  const float* k_w = (const float*)d_in[3];
  const float* k_b = (const float*)d_in[4];
  const float* v_w = (const float*)d_in[5];
  const float* v_b = (const float*)d_in[6];
  const float* o_w = (const float*)d_in[7];
  const float* o_b = (const float*)d_in[8];

  char* ws = (char*)d_ws;
  // Wqt/Wvt/Wkt are contiguous: together one [9216][1024] bf16 matrix.
  bf16* Xb  = (bf16*)(ws);                    //  8 MiB: X bf16 [4096][1024]
  bf16* Wqt = (bf16*)(ws + 8388608);          //  6 MiB: q_w^T [3072][1024]
  bf16* Wvt = (bf16*)(ws + 14680064);         //  6 MiB: v_w^T (-> k_mat)
  bf16* Wkt = (bf16*)(ws + 20971520);         //  6 MiB: k_w^T (-> v_mat)
  bf16* Wot = (bf16*)(ws + 27262976);         //  6 MiB: o_w^T [1024][3072]
  bf16* Qm  = (bf16*)(ws + 33554432);         // 24 MiB: Q [4096][3072]
  bf16* Km  = (bf16*)(ws + 58720256);         // 24 MiB: K-attn [4096][3072]
  bf16* Vtw = (bf16*)(ws + 83886080);         // 24 MiB: V-attn^T [32][192][2048]
  bf16* Im  = (bf16*)(ws + 109051904);        // 24 MiB: inter [4096][3072]

  cvt_x_kernel<<<4096, 256, 0, stream>>>(X, Xb);
  transpose_cvt_kernel<<<3072, 256, 0, stream>>>(q_w, Wqt, 1024, 3072);
  transpose_cvt_kernel<<<3072, 256, 0, stream>>>(v_w, Wvt, 1024, 3072);
  transpose_cvt_kernel<<<3072, 256, 0, stream>>>(k_w, Wkt, 1024, 3072);
  transpose_cvt_kernel<<<3072, 256, 0, stream>>>(o_w, Wot, 3072, 1024);

  // fused Q/K/V projection (quirk: seg1 = X@v_w+v_b -> Km, seg2 = X@k_w+k_b -> V)
  gemm_fused_qkv<<<1536, 512, 0, stream>>>(Xb, Wqt, q_b, v_b, k_b, Qm, Km, Vtw);

  attn_kernel<<<256, 512, 0, stream>>>(Qm, Km, Vtw, Im);

  gemm_bf16_kernel<2><<<256, 256, 0, stream>>>(Im, Wot, o_b, d_out, 4096, 1024, 3072);
}

// Round 13
// 277.529 us; speedup vs baseline: 1.2559x; 1.0983x over previous
//
#include <hip/hip_runtime.h>
#include <cstdint>
#include <cstddef>

typedef __bf16 bf16;
typedef __attribute__((ext_vector_type(8))) __bf16 bf16x8;
typedef __attribute__((ext_vector_type(4))) __bf16 bf16x4;
typedef __attribute__((ext_vector_type(2))) __bf16 bf16x2;
typedef __attribute__((ext_vector_type(4))) float f32x4;

#define MFMA_16x16x32(a, b, c) __builtin_amdgcn_mfma_f32_16x16x32_bf16((a), (b), (c), 0, 0, 0)

__device__ __forceinline__ void gload_lds16(const void* g, void* l) {
  __builtin_amdgcn_global_load_lds((__attribute__((address_space(1))) void*)g,
                                   (__attribute__((address_space(3))) void*)l,
                                   16, 0, 0);
}

// ---------------------------------------------------------------------------
// fp32 -> bf16 convert (grid covers exactly n/4 elements, n = 4096*1024)
// ---------------------------------------------------------------------------
__global__ __launch_bounds__(256) void cvt_x_kernel(const float* __restrict__ in,
                                                    bf16* __restrict__ out) {
  int i = blockIdx.x * 256 + threadIdx.x;
  float4 v = ((const float4*)in)[i];
  bf16x4 o = {(bf16)v.x, (bf16)v.y, (bf16)v.z, (bf16)v.w};
  ((bf16x4*)out)[i] = o;
}

// ---------------------------------------------------------------------------
// transpose + convert: in fp32 [R][C] -> out bf16 [C][R]
// ---------------------------------------------------------------------------
__global__ __launch_bounds__(256) void transpose_cvt_kernel(const float* __restrict__ in,
                                                            bf16* __restrict__ out,
                                                            int R, int C) {
  __shared__ float tile[32][33];
  int tiles_c = C >> 5;
  int br = (int)blockIdx.x / tiles_c, bc = (int)blockIdx.x % tiles_c;
  int r0 = br << 5, c0 = bc << 5;
  int tr = threadIdx.x >> 5, tc = threadIdx.x & 31;
#pragma unroll
  for (int i = 0; i < 4; i++)
    tile[tr + 8 * i][tc] = in[(size_t)(r0 + tr + 8 * i) * C + c0 + tc];
  __syncthreads();
#pragma unroll
  for (int i = 0; i < 4; i++) {
    int oc = tr + 8 * i;
    out[(size_t)(c0 + oc) * R + r0 + tc] = (bf16)tile[tc][oc];
  }
}

// ---------------------------------------------------------------------------
// fused 3-weight transpose+convert: q_w/v_w/k_w (each fp32 [1024][3072])
// -> contiguous bf16 [9216][1024] at out.  One launch instead of three.
// ---------------------------------------------------------------------------
__global__ __launch_bounds__(256) void transpose_cvt3_kernel(const float* __restrict__ q_w,
                                                             const float* __restrict__ v_w,
                                                             const float* __restrict__ k_w,
                                                             bf16* __restrict__ out) {
  __shared__ float tile[32][33];
  int widx = (int)blockIdx.x / 3072;
  int blk = (int)blockIdx.x % 3072;
  const float* in = widx == 0 ? q_w : (widx == 1 ? v_w : k_w);
  bf16* o = out + (size_t)widx * 3072 * 1024;
  int br = blk / 96, bc = blk % 96;  // R=1024 (32 tiles), C=3072 (96 tiles)
  int r0 = br << 5, c0 = bc << 5;
  int tr = threadIdx.x >> 5, tc = threadIdx.x & 31;
#pragma unroll
  for (int i = 0; i < 4; i++)
    tile[tr + 8 * i][tc] = in[(size_t)(r0 + tr + 8 * i) * 3072 + c0 + tc];
  __syncthreads();
#pragma unroll
  for (int i = 0; i < 4; i++) {
    int oc = tr + 8 * i;
    o[(size_t)(c0 + oc) * 1024 + r0 + tc] = (bf16)tile[tc][oc];
  }
}

// ---------------------------------------------------------------------------
// Fused QKV projection GEMM v3 (round 12, unchanged): 128x192 tile,
// 2 blocks/CU, 2-phase counted-vmcnt(5) per K-tile.
// ---------------------------------------------------------------------------
__global__ __launch_bounds__(512, 2) void gemm_fused_qkv(
    const bf16* __restrict__ A, const bf16* __restrict__ Bt,
    const float* __restrict__ q_b, const float* __restrict__ v_b,
    const float* __restrict__ k_b,
    bf16* __restrict__ Qm, bf16* __restrict__ Km, bf16* __restrict__ Vt) {
  constexpr int K = 1024, NT = 16;  // K-tiles of 64
  __shared__ __align__(16) bf16 sA[2][2][128 * 32];  // 32 KB
  __shared__ __align__(16) bf16 sB[2][192 * 64];     // 48 KB

  int bid = blockIdx.x;
  int xcd = bid & 7, j = bid >> 3;
  int bm = xcd * 4 + (j & 3), bn = j >> 2;
  int m0 = bm << 7, n0 = bn * 192;

  int tid = threadIdx.x, lane = tid & 63, w = tid >> 6;
  int wr = w >> 2, wc = w & 3;
  int l15 = lane & 15, lg = lane >> 4;

  int sra = lane >> 2, sca = lane & 3;
  const bf16* gA = A + (size_t)(m0 + w * 16 + sra) * K + ((sca ^ ((sra >> 1) & 3)) * 8);
  int srb = lane >> 3, scb = lane & 7;
  const bf16* gB = Bt + (size_t)(n0 + w * 24 + srb) * K + ((scb ^ srb) * 8);

#define STAGE_AB(BUF, T)                                                   \
  {                                                                        \
    _Pragma("unroll") for (int kh = 0; kh < 2; kh++)                       \
        gload_lds16(gA + (size_t)(T) * 64 + kh * 32, &sA[BUF][kh][w * 512]); \
    _Pragma("unroll") for (int ii = 0; ii < 3; ii++)                       \
        gload_lds16(gB + (size_t)(ii * 8) * K + (T) * 64,                  \
                    &sB[BUF][(w * 3 + ii) * 512]);                         \
  }
#define VMCNT(N) asm volatile("s_waitcnt vmcnt(" #N ")" ::: "memory")
#define LGK0                                           \
  {                                                    \
    asm volatile("s_waitcnt lgkmcnt(0)" ::: "memory"); \
    __builtin_amdgcn_sched_barrier(0);                 \
  }

  int slotA = lg ^ ((l15 >> 1) & 3);
  int aBase = wr * 2048 + l15 * 32 + slotA * 8;
  int bBase = (wc * 48 + l15) * 64;
  int sB0 = (lg ^ (l15 & 7)) * 8;
  int sB1 = ((4 + lg) ^ (l15 & 7)) * 8;

#define RD_A(BUF, KH)                                                      \
  _Pragma("unroll") for (int mf = 0; mf < 4; mf++)                         \
      a[mf] = *(const bf16x8*)&sA[BUF][KH][aBase + mf * 512];
#define RD_B(BUF, SLOT)                                                    \
  _Pragma("unroll") for (int nf = 0; nf < 3; nf++)                         \
      b[nf] = *(const bf16x8*)&sB[BUF][bBase + nf * 1024 + (SLOT)];
#define MFMA12                                                             \
  _Pragma("unroll") for (int mf = 0; mf < 4; mf++)                         \
      _Pragma("unroll") for (int nf = 0; nf < 3; nf++)                     \
          acc[mf][nf] = MFMA_16x16x32(a[mf], b[nf], acc[mf][nf]);

  f32x4 acc[4][3];
#pragma unroll
  for (int mf = 0; mf < 4; mf++)
#pragma unroll
    for (int nf = 0; nf < 3; nf++) acc[mf][nf] = (f32x4){0.f, 0.f, 0.f, 0.f};

  STAGE_AB(0, 0);

#pragma unroll 2
  for (int s = 0; s < NT; s++) {
    int buf = s & 1, nbuf = buf ^ 1;
    int nxt = (s + 1) & (NT - 1);
    bf16x8 a[4], b[3];

    STAGE_AB(nbuf, nxt);
    VMCNT(5);
    __builtin_amdgcn_s_barrier();

    // ---- ph1: ks0
    RD_A(buf, 0);
    RD_B(buf, sB0);
    LGK0;
    __builtin_amdgcn_s_setprio(1);
    MFMA12;
    __builtin_amdgcn_s_setprio(0);

    // ---- ph2: ks1
    RD_A(buf, 1);
    RD_B(buf, sB1);
    LGK0;
    __builtin_amdgcn_s_barrier();  // release buf for next iter's STAGE
    __builtin_amdgcn_s_setprio(1);
    MFMA12;
    __builtin_amdgcn_s_setprio(0);
  }

  // ---- epilogue: route by N-segment
  int seg = bn >> 4;
  int segbn = bn & 15;
  const float* bias = seg == 0 ? q_b : (seg == 1 ? v_b : k_b);
  bf16* outQK = seg == 0 ? Qm : Km;
#pragma unroll
  for (int mf = 0; mf < 4; mf++) {
#pragma unroll
    for (int nf = 0; nf < 3; nf++) {
      int colL = segbn * 192 + wc * 48 + nf * 16 + l15;
      int row0 = m0 + wr * 64 + mf * 16 + lg * 4;
      float bv = bias[colL];
      if (seg < 2) {
#pragma unroll
        for (int r = 0; r < 4; r++)
          outQK[(size_t)(row0 + r) * 3072 + colL] = (bf16)(acc[mf][nf][r] + bv);
      } else {
        int hh = colL / 192, dd = colL % 192;
        int bi = row0 >> 11, nn = row0 & 2047;
        bf16x4 pk = {(bf16)(acc[mf][nf][0] + bv), (bf16)(acc[mf][nf][1] + bv),
                     (bf16)(acc[mf][nf][2] + bv), (bf16)(acc[mf][nf][3] + bv)};
        *(bf16x4*)(Vt + (((size_t)bi * 16 + hh) * 192 + dd) * 2048 + nn) = pk;
      }
    }
  }
#undef STAGE_AB
#undef RD_A
#undef RD_B
#undef MFMA12
}

// ---------------------------------------------------------------------------
// Output projection GEMM v3: C = Im @ o_w + o_b, fp32 out [4096][1024].
// 128x64 tile, grid 512 (32 bm x 16 bn) = 2.0 rounds at 3 blocks/CU.
// 4 waves (2M x 2N), per-wave 64x32 (acc[4][2]).  K=3072 -> 48 K-tiles
// (deep pipeline, fill/drain ~2%).  LDS 48 KB: sA[2][2][128x32] +
// sB[2][2][64x32], chunk-swizzled (slot = lg ^ ((row>>1)&3), inverse on
// global source) -> 2-way residual bank conflicts (free).
// Same 2-phase counted-vmcnt schedule as QKV v3: stage all 6 loads of
// tile s+1 at iter top; vmcnt(6) drains exactly tile s.
// ---------------------------------------------------------------------------
__global__ __launch_bounds__(256, 3) void gemm_oproj(const bf16* __restrict__ A,
                                                     const bf16* __restrict__ Bt,
                                                     const float* __restrict__ bias,
                                                     float* __restrict__ out) {
  constexpr int K = 3072, NT = 48;  // K-tiles of 64
  __shared__ __align__(16) bf16 sA[2][2][128 * 32];  // 32 KB
  __shared__ __align__(16) bf16 sB[2][2][64 * 32];   // 16 KB

  // XCD swizzle: 512 = 8 XCDs x 64; per XCD 4 bm x 16 bn.
  int bid = blockIdx.x;
  int xcd = bid & 7, j = bid >> 3;           // j 0..63
  int bm = xcd * 4 + (j & 3), bn = j >> 2;   // bm 0..31, bn 0..15
  int m0 = bm << 7, n0 = bn << 6;

  int tid = threadIdx.x, lane = tid & 63, w = tid >> 6;  // 4 waves
  int wr = w >> 1, wc = w & 1;
  int l15 = lane & 15, lg = lane >> 4;

  // staging: regions of 16 rows x 4 chunks (16B); inverse swizzle on source
  int sra = lane >> 2, sca = lane & 3;
  int swzS = (sca ^ ((sra >> 1) & 3)) * 8;
  const bf16* gA = A + (size_t)(m0 + w * 32 + sra) * K + swzS;
  const bf16* gB = Bt + (size_t)(n0 + w * 16 + sra) * K + swzS;

#define O_STAGE(BUF, T)                                                     \
  {                                                                         \
    _Pragma("unroll") for (int kh = 0; kh < 2; kh++) {                      \
      _Pragma("unroll") for (int ii = 0; ii < 2; ii++)                      \
          gload_lds16(gA + (size_t)(ii * 16) * K + (T) * 64 + kh * 32,      \
                      &sA[BUF][kh][(w * 32 + ii * 16) * 32]);               \
      gload_lds16(gB + (size_t)(T) * 64 + kh * 32, &sB[BUF][kh][w * 512]);  \
    }                                                                       \
  }

  int slotA = lg ^ ((l15 >> 1) & 3);
  int aBase = (wr * 64 + l15) * 32 + slotA * 8;
  int bBase = (wc * 32 + l15) * 32 + slotA * 8;

#define O_RD(BUF, KH)                                                      \
  {                                                                        \
    _Pragma("unroll") for (int mf = 0; mf < 4; mf++)                       \
        a[mf] = *(const bf16x8*)&sA[BUF][KH][aBase + mf * 512];             \
    _Pragma("unroll") for (int nf = 0; nf < 2; nf++)                       \
        b[nf] = *(const bf16x8*)&sB[BUF][KH][bBase + nf * 512];             \
  }
#define O_MFMA8                                                            \
  _Pragma("unroll") for (int mf = 0; mf < 4; mf++)                         \
      _Pragma("unroll") for (int nf = 0; nf < 2; nf++)                     \
          acc[mf][nf] = MFMA_16x16x32(a[mf], b[nf], acc[mf][nf]);

  f32x4 acc[4][2];
#pragma unroll
  for (int mf = 0; mf < 4; mf++)
#pragma unroll
    for (int nf = 0; nf < 2; nf++) acc[mf][nf] = (f32x4){0.f, 0.f, 0.f, 0.f};

  O_STAGE(0, 0);  // prologue: tile 0 (6 loads/lane)

#pragma unroll 2
  for (int s = 0; s < NT; s++) {
    int buf = s & 1, nbuf = buf ^ 1;
    int nxt = s + 1 < NT ? s + 1 : 0;
    bf16x8 a[4], b[2];

    O_STAGE(nbuf, nxt);  // 6 loads for tile s+1
    VMCNT(6);            // drain exactly tile s (issued one full iter ago)
    __builtin_amdgcn_s_barrier();

    // ---- ph1: kh0
    O_RD(buf, 0);
    LGK0;
    __builtin_amdgcn_s_setprio(1);
    O_MFMA8;
    __builtin_amdgcn_s_setprio(0);

    // ---- ph2: kh1
    O_RD(buf, 1);
    LGK0;
    __builtin_amdgcn_s_barrier();  // release buf for next iter's STAGE
    __builtin_amdgcn_s_setprio(1);
    O_MFMA8;
    __builtin_amdgcn_s_setprio(0);
  }

  // ---- epilogue: fp32 out + bias
#pragma unroll
  for (int mf = 0; mf < 4; mf++) {
#pragma unroll
    for (int nf = 0; nf < 2; nf++) {
      int col = n0 + wc * 32 + nf * 16 + l15;
      int row0 = m0 + wr * 64 + mf * 16 + lg * 4;
      float bv = bias[col];
#pragma unroll
      for (int r = 0; r < 4; r++)
        out[(size_t)(row0 + r) * 1024 + col] = acc[mf][nf][r] + bv;
    }
  }
#undef O_STAGE
#undef O_RD
#undef O_MFMA8
#undef VMCNT
#undef LGK0
}

// ---------------------------------------------------------------------------
// Flash attention (r5/r9 known-good version): swapped-S^T, global_load_lds
// double-buffered K/V, 8 waves x 32 q-rows, XOR-swizzled both-sides staging.
// ---------------------------------------------------------------------------
__global__ __launch_bounds__(512, 2) void attn_kernel(const bf16* __restrict__ Q,
                                                      const bf16* __restrict__ Km,
                                                      const bf16* __restrict__ Vt,
                                                      bf16* __restrict__ inter) {
  __shared__ __align__(16) bf16 sK[2][64 * 192];
  __shared__ __align__(16) bf16 sV[2][192 * 64];
  __shared__ __align__(16) bf16 sPT[8 * 2 * 16 * 72];

  int i = blockIdx.x;
  int j = i >> 3;
  int bh = (i & 7) * 4 + (j >> 3);
  int qt = j & 7;
  int b = bh >> 4, h = bh & 15;
  int tid = threadIdx.x, lane = tid & 63, w = tid >> 6;
  int l15 = lane & 15, lg = lane >> 4;
  int swz = l15 & 7;

  const bf16* Qh = Q + (size_t)b * 2048 * 3072 + (size_t)h * 192;
  const bf16* Kh = Km + (size_t)b * 2048 * 3072 + (size_t)h * 192;
  const bf16* Vh = Vt + (size_t)bh * 192 * 2048;

  int q0 = qt * 256 + w * 32;

  int kOff[3], vOff[3], ldsOff[3];
#pragma unroll
  for (int ii = 0; ii < 3; ii++) {
    int r = ii * 8 + w;
    int s = r * 64 + lane;
    int krow = s / 24, kc = s % 24;
    int kcs = (kc & 24) | ((kc & 7) ^ (krow & 7));
    kOff[ii] = krow * 3072 + kcs * 8;
    int vrow = s >> 3, vc = s & 7;
    int vcs = vc ^ (vrow & 7);
    vOff[ii] = vrow * 2048 + vcs * 8;
    ldsOff[ii] = r * 512;
  }

#define STAGE(BUF, KT)                                                      \
  {                                                                         \
    int kb = (KT) * 64;                                                     \
    _Pragma("unroll") for (int ii = 0; ii < 3; ii++) {                      \
      gload_lds16(Kh + (size_t)kb * 3072 + kOff[ii], &sK[BUF][ldsOff[ii]]); \
      gload_lds16(Vh + kb + vOff[ii], &sV[BUF][ldsOff[ii]]);                \
    }                                                                       \
  }

  STAGE(0, 0);

  bf16x8 aq[2][6];
#pragma unroll
  for (int rf = 0; rf < 2; rf++)
#pragma unroll
    for (int kc = 0; kc < 6; kc++)
      aq[rf][kc] = *(const bf16x8*)(Qh + (size_t)(q0 + rf * 16 + l15) * 3072 + kc * 32 + lg * 8);

  f32x4 o[2][12];
#pragma unroll
  for (int rf = 0; rf < 2; rf++)
#pragma unroll
    for (int df = 0; df < 12; df++) o[rf][df] = (f32x4){0.f, 0.f, 0.f, 0.f};
  float mrow[2] = {-1e30f, -1e30f};
  float lrow[2] = {0.f, 0.f};

  const float scl2 = 0.03125f * 1.44269504f;

  bf16* myPT0 = &sPT[((w * 2 + 0) * 16 + l15) * 72];
  bf16* myPT1 = &sPT[((w * 2 + 1) * 16 + l15) * 72];

  __syncthreads();

  for (int kt = 0; kt < 32; kt++) {
    const bf16* kbuf = sK[kt & 1];
    const bf16* vbuf = sV[kt & 1];
    if (kt < 31) STAGE((kt & 1) ^ 1, kt + 1);

    f32x4 st[4][2];
#pragma unroll
    for (int kf = 0; kf < 4; kf++)
#pragma unroll
      for (int rf = 0; rf < 2; rf++) st[kf][rf] = (f32x4){0.f, 0.f, 0.f, 0.f};
    __builtin_amdgcn_s_setprio(1);
#pragma unroll
    for (int kc = 0; kc < 6; kc++) {
      int g = kc * 4 + lg;
      int cc = (g & 24) | ((g & 7) ^ swz);
#pragma unroll
      for (int kf = 0; kf < 4; kf++) {
        bf16x8 bk = *(const bf16x8*)&kbuf[(kf * 16 + l15) * 192 + cc * 8];
        st[kf][0] = MFMA_16x16x32(bk, aq[0][kc], st[kf][0]);
        st[kf][1] = MFMA_16x16x32(bk, aq[1][kc], st[kf][1]);
      }
    }
    __builtin_amdgcn_s_setprio(0);

#pragma unroll
    for (int rf = 0; rf < 2; rf++) {
      bf16* myPT = rf ? myPT1 : myPT0;
      float mk[4];
#pragma unroll
      for (int kf = 0; kf < 4; kf++)
        mk[kf] = fmaxf(fmaxf(st[kf][rf][0], st[kf][rf][1]),
                       fmaxf(st[kf][rf][2], st[kf][rf][3]));
      float pmx = fmaxf(fmaxf(mk[0], mk[1]), fmaxf(mk[2], mk[3]));
      pmx = fmaxf(pmx, __shfl_xor(pmx, 16));
      pmx = fmaxf(pmx, __shfl_xor(pmx, 32));
      float pms = pmx * scl2;

      float mn = mrow[rf];
      if (!__all(pms - mn <= 11.0f)) {
        mn = fmaxf(mn, pms);
        float corr = exp2f(mrow[rf] - mn);
        mrow[rf] = mn;
        lrow[rf] *= corr;
#pragma unroll
        for (int df = 0; df < 12; df++) o[rf][df] *= corr;
      }

      float skf[4];
#pragma unroll
      for (int kf = 0; kf < 4; kf++) {
        float e0 = exp2f(fmaf(st[kf][rf][0], scl2, -mn));
        float e1 = exp2f(fmaf(st[kf][rf][1], scl2, -mn));
        float e2 = exp2f(fmaf(st[kf][rf][2], scl2, -mn));
        float e3 = exp2f(fmaf(st[kf][rf][3], scl2, -mn));
        skf[kf] = (e0 + e1) + (e2 + e3);
        bf16x4 pk4 = {(bf16)e0, (bf16)e1, (bf16)e2, (bf16)e3};
        *(bf16x4*)&myPT[kf * 16 + 4 * lg] = pk4;
      }
      float rs = (skf[0] + skf[1]) + (skf[2] + skf[3]);
      rs += __shfl_xor(rs, 16);
      rs += __shfl_xor(rs, 32);
      lrow[rf] += rs;
    }

    bf16x8 pf[2][2];
#pragma unroll
    for (int rf = 0; rf < 2; rf++) {
      bf16* myPT = rf ? myPT1 : myPT0;
#pragma unroll
      for (int ks = 0; ks < 2; ks++)
        pf[rf][ks] = *(const bf16x8*)&myPT[ks * 32 + lg * 8];
    }

    __builtin_amdgcn_s_setprio(1);
#pragma unroll
    for (int ks = 0; ks < 2; ks++) {
      int cv = (ks * 4 + lg) ^ swz;
#pragma unroll
      for (int df = 0; df < 12; df++) {
        bf16x8 av = *(const bf16x8*)&vbuf[(df * 16 + l15) * 64 + cv * 8];
        o[0][df] = MFMA_16x16x32(av, pf[0][ks], o[0][df]);
        o[1][df] = MFMA_16x16x32(av, pf[1][ks], o[1][df]);
      }
    }
    __builtin_amdgcn_s_setprio(0);

    __syncthreads();
  }

#pragma unroll
  for (int rf = 0; rf < 2; rf++) {
    float inv = 1.0f / lrow[rf];
    size_t token = (size_t)b * 2048 + q0 + rf * 16 + l15;
    bf16* outp = inter + token * 3072 + h * 192 + lg * 4;
#pragma unroll
    for (int df = 0; df < 12; df++) {
      bf16x4 pk = {(bf16)(o[rf][df][0] * inv), (bf16)(o[rf][df][1] * inv),
                   (bf16)(o[rf][df][2] * inv), (bf16)(o[rf][df][3] * inv)};
      *(bf16x4*)(outp + df * 16) = pk;
    }
  }
#undef STAGE
}

// ---------------------------------------------------------------------------
extern "C" void kernel_launch(void* const* d_in, const int* in_sizes, int n_in,
                              void* d_out, int out_size, void* d_ws, size_t ws_size,
                              hipStream_t stream) {
  const float* X = (const float*)d_in[0];
  const float* q_w = (const float*)d_in[1];
  const float* q_b = (const float*)d_in[2];
  const float* k_w = (const float*)d_in[3];
  const float* k_b = (const float*)d_in[4];
  const float* v_w = (const float*)d_in[5];
  const float* v_b = (const float*)d_in[6];
  const float* o_w = (const float*)d_in[7];
  const float* o_b = (const float*)d_in[8];

  char* ws = (char*)d_ws;
  // Wqt/Wvt/Wkt are contiguous: together one [9216][1024] bf16 matrix.
  bf16* Xb  = (bf16*)(ws);                    //  8 MiB: X bf16 [4096][1024]
  bf16* Wqt = (bf16*)(ws + 8388608);          //  6 MiB: q_w^T [3072][1024]
  bf16* Wot = (bf16*)(ws + 27262976);         //  6 MiB: o_w^T [1024][3072]
  bf16* Qm  = (bf16*)(ws + 33554432);         // 24 MiB: Q [4096][3072]
  bf16* Km  = (bf16*)(ws + 58720256);         // 24 MiB: K-attn [4096][3072]
  bf16* Vtw = (bf16*)(ws + 83886080);         // 24 MiB: V-attn^T [32][192][2048]
  bf16* Im  = (bf16*)(ws + 109051904);        // 24 MiB: inter [4096][3072]

  cvt_x_kernel<<<4096, 256, 0, stream>>>(X, Xb);
  // quirk preserved downstream: widx1 = v_w (-> Km), widx2 = k_w (-> V)
  transpose_cvt3_kernel<<<9216, 256, 0, stream>>>(q_w, v_w, k_w, Wqt);
  transpose_cvt_kernel<<<3072, 256, 0, stream>>>(o_w, Wot, 3072, 1024);

  // fused Q/K/V projection (quirk: seg1 = X@v_w+v_b -> Km, seg2 = X@k_w+k_b -> V)
  gemm_fused_qkv<<<1536, 512, 0, stream>>>(Xb, Wqt, q_b, v_b, k_b, Qm, Km, Vtw);

  attn_kernel<<<256, 512, 0, stream>>>(Qm, Km, Vtw, Im);

  gemm_oproj<<<512, 256, 0, stream>>>(Im, Wot, o_b, (float*)d_out);
}